// Round 3
// baseline (2132.975 us; speedup 1.0000x reference)
//
#include <hip/hip_runtime.h>
#include <hip/hip_bf16.h>
#include <math.h>

#define N_NODES 10000
#define N_EDGES 80000
#define N_ORI   12
#define N_ROWS  (N_NODES * N_ORI)

__device__ __forceinline__ float gelu_f(float x) {
    return 0.5f * x * (1.0f + erff(x * 0.70710678118654752440f));
}

// ---------------------------------------------------------------------------
// K0: transpose W1 (64x256 -> [t][k]) and W2 (256x64 -> [c][t]) per layer.
// ---------------------------------------------------------------------------
__global__ __launch_bounds__(256) void transpose_w(
    const float* __restrict__ W1, const float* __restrict__ W2,
    float* __restrict__ W1T, float* __restrict__ W2T)
{
    int l = blockIdx.x;
    const float* w1 = W1 + l*16384; float* w1t = W1T + l*16384;
    const float* w2 = W2 + l*16384; float* w2t = W2T + l*16384;
    for (int i = threadIdx.x; i < 16384; i += 256) {
        w1t[(i & 255)*64 + (i >> 8)] = w1[i];   // W1[k][t] -> W1T[t][k]
        w2t[(i & 63)*256 + (i >> 6)] = w2[i];   // W2[t][c] -> W2T[c][t]
    }
}

// ---------------------------------------------------------------------------
// K1: kb_ori MLP + fk[l][p][o][c] = (kb_ori @ Wf[l]).  144 blocks x 64.
// ---------------------------------------------------------------------------
__global__ __launch_bounds__(64) void ori_kernel(
    const float* __restrict__ ori, const float* __restrict__ Wo1,
    const float* __restrict__ bo1, const float* __restrict__ Wo2,
    const float* __restrict__ bo2, const float* __restrict__ Wf,
    float* __restrict__ fkb)
{
    __shared__ float sh[64];
    __shared__ float skb[64];
    int i = blockIdx.x / 12, j = blockIdx.x % 12;
    int lane = threadIdx.x;
    float s = ori[3*i]*ori[3*j] + ori[3*i+1]*ori[3*j+1] + ori[3*i+2]*ori[3*j+2];
    float p1 = s, p2 = s*s, p3 = p2*s, p4 = p3*s;
    float acc = bo1[lane] + p1*Wo1[lane] + p2*Wo1[64+lane] + p3*Wo1[128+lane] + p4*Wo1[192+lane];
    sh[lane] = gelu_f(acc);
    __syncthreads();
    float acc2 = bo2[lane];
    #pragma unroll
    for (int k = 0; k < 64; k++) acc2 += sh[k] * Wo2[k*64 + lane];
    skb[lane] = gelu_f(acc2);
    __syncthreads();
    for (int l = 0; l < 2; l++) {
        float a = 0.f;
        #pragma unroll
        for (int k = 0; k < 64; k++) a += skb[k] * Wf[l*4096 + k*64 + lane];
        fkb[l*9216 + i*768 + j*64 + lane] = a;
    }
}

// ---------------------------------------------------------------------------
// K2: x = f @ We
// ---------------------------------------------------------------------------
__global__ __launch_bounds__(256) void embed_kernel(
    const float* __restrict__ f, const float* __restrict__ We, float* __restrict__ xe)
{
    int v = blockIdx.x*4 + (threadIdx.x >> 6);
    int lane = threadIdx.x & 63;
    if (v >= N_NODES) return;
    float acc = 0.f;
    #pragma unroll
    for (int k = 0; k < 16; k++) acc += f[v*16 + k] * We[k*64 + lane];
    xe[v*64 + lane] = acc;
}

// ---------------------------------------------------------------------------
// K3: kb[e,o,c] = gelu(gelu(poly @ Wb1) @ Wb2) * env(d), stored bf16. ONCE.
// ---------------------------------------------------------------------------
__global__ __launch_bounds__(256) void kb_kernel(
    const float* __restrict__ pos, const float* __restrict__ ori,
    const float* __restrict__ Wb1, const float* __restrict__ bb1,
    const float* __restrict__ Wb2, const float* __restrict__ bb2,
    const int* __restrict__ ei, __hip_bfloat16* __restrict__ kbb)
{
    __shared__ float sh1[4][64];
    int w = threadIdx.x >> 6, lane = threadIdx.x & 63;

    float wb1c[30], wb2c[64];
    #pragma unroll
    for (int k = 0; k < 30; k++) wb1c[k] = Wb1[k*64 + lane];
    #pragma unroll
    for (int k = 0; k < 64; k++) wb2c[k] = Wb2[k*64 + lane];
    float bb1l = bb1[lane], bb2l = bb2[lane];

    int e  = blockIdx.x*4 + w;
    int sn = ei[e], dn = ei[N_EDGES + e];
    float rx = pos[sn*3+0] - pos[dn*3+0];
    float ry = pos[sn*3+1] - pos[dn*3+1];
    float rz = pos[sn*3+2] - pos[dn*3+2];
    float d  = sqrtf(rx*rx + ry*ry + rz*rz);
    float u2 = d*d, u4 = u2*u2, u6 = u4*u2;
    float env = (d < 1.0f) ? (1.0f - 28.0f*u6 + 48.0f*u6*d - 21.0f*u6*u2) : 0.0f;
    __hip_bfloat16* kbrow = kbb + (size_t)e*768;

    for (int o = 0; o < N_ORI; o++) {
        float ox = ori[3*o], oy = ori[3*o+1], oz = ori[3*o+2];
        float a  = rx*ox + ry*oy + rz*oz;
        float qx = rx - a*ox, qy = ry - a*oy, qz = rz - a*oz;
        float b  = sqrtf(qx*qx + qy*qy + qz*qz);
        float acc = bb1l + a*wb1c[0] + b*wb1c[1];
        float c0 = a*a, c1 = a*b, c2 = b*a, c3 = b*b;
        acc += c0*wb1c[2] + c1*wb1c[3] + c2*wb1c[4] + c3*wb1c[5];
        float d0=c0*a,d1=c0*b,d2=c1*a,d3=c1*b,d4=c2*a,d5=c2*b,d6=c3*a,d7=c3*b;
        acc += d0*wb1c[6]+d1*wb1c[7]+d2*wb1c[8]+d3*wb1c[9]
             + d4*wb1c[10]+d5*wb1c[11]+d6*wb1c[12]+d7*wb1c[13];
        acc += d0*a*wb1c[14]+d0*b*wb1c[15]+d1*a*wb1c[16]+d1*b*wb1c[17]
             + d2*a*wb1c[18]+d2*b*wb1c[19]+d3*a*wb1c[20]+d3*b*wb1c[21]
             + d4*a*wb1c[22]+d4*b*wb1c[23]+d5*a*wb1c[24]+d5*b*wb1c[25]
             + d6*a*wb1c[26]+d6*b*wb1c[27]+d7*a*wb1c[28]+d7*b*wb1c[29];
        sh1[w][lane] = gelu_f(acc);
        __builtin_amdgcn_wave_barrier();
        float acc2 = bb2l;
        const float4* h4 = (const float4*)(&sh1[w][0]);
        #pragma unroll
        for (int k4 = 0; k4 < 16; k4++) {
            float4 hv = h4[k4];
            acc2 += hv.x*wb2c[4*k4] + hv.y*wb2c[4*k4+1] + hv.z*wb2c[4*k4+2] + hv.w*wb2c[4*k4+3];
        }
        __builtin_amdgcn_wave_barrier();
        kbrow[o*64 + lane] = __float2bfloat16(gelu_f(acc2) * env);
    }
}

// ---------------------------------------------------------------------------
// K4: per-layer scatter: msg = x[src] * (kb @ Wk[l]); atomicAdd into x1[dst].
// ---------------------------------------------------------------------------
__global__ __launch_bounds__(256) void scatter_kernel(
    const __hip_bfloat16* __restrict__ kbb, const float* __restrict__ Wk,
    const int* __restrict__ ei, const float* __restrict__ x_in,
    float* __restrict__ x1, int has_ori)
{
    __shared__ float skb[4][64];
    int w = threadIdx.x >> 6, lane = threadIdx.x & 63;
    float wkc[64];
    #pragma unroll
    for (int k = 0; k < 64; k++) wkc[k] = Wk[k*64 + lane];

    int e  = blockIdx.x*4 + w;
    int sn = ei[e], dn = ei[N_EDGES + e];
    const __hip_bfloat16* kbrow = kbb + (size_t)e*768;
    const float* xsrc  = x_in + (has_ori ? (size_t)sn*768 : (size_t)sn*64);
    float*       x1row = x1 + (size_t)dn*768;
    float xs0 = has_ori ? 0.f : xsrc[lane];

    for (int o = 0; o < N_ORI; o++) {
        skb[w][lane] = __bfloat162float(kbrow[o*64 + lane]);
        __builtin_amdgcn_wave_barrier();
        float accm = 0.f;
        const float4* kb4 = (const float4*)(&skb[w][0]);
        #pragma unroll
        for (int k4 = 0; k4 < 16; k4++) {
            float4 kv = kb4[k4];
            accm += kv.x*wkc[4*k4] + kv.y*wkc[4*k4+1] + kv.z*wkc[4*k4+2] + kv.w*wkc[4*k4+3];
        }
        __builtin_amdgcn_wave_barrier();
        float xs = has_ori ? xsrc[o*64 + lane] : xs0;
        atomicAdd(&x1row[o*64 + lane], xs * accm);
    }
}

// ---------------------------------------------------------------------------
// K5: per-row conv-contract + LN + FFN (+res) + readout.
// PAIR-SPLIT: two waves share 64 rows; wave0 computes hidden t=[0,128),
// wave1 t=[128,256); partials summed via stride-65 LDS tile (conflict-free).
// __launch_bounds__(256,2): no spills (live state ~165 regs). Grid 938 blocks
// -> 3750 waves = 3.66 waves/SIMD (2x round-2's 1.83).
// ---------------------------------------------------------------------------
__global__ __launch_bounds__(256, 2) void node_kernel(
    const float* __restrict__ x1, const float* __restrict__ fk,
    const float* __restrict__ conv_b, const float* __restrict__ ln_g,
    const float* __restrict__ ln_b,
    const float* __restrict__ W1T, const float* __restrict__ b1,
    const float* __restrict__ W2T, const float* __restrict__ b2,
    const float* __restrict__ Wr, const float* __restrict__ br,
    const float* __restrict__ x_old, float* __restrict__ x_new,
    float* __restrict__ racc, int has_res, int write_x)
{
    __shared__ float sOut[2][64*65];
    int lane = threadIdx.x & 63;
    int half = __builtin_amdgcn_readfirstlane((threadIdx.x >> 6) & 1); // scalar
    int pair = __builtin_amdgcn_readfirstlane(threadIdx.x >> 7);
    int rowBase = (blockIdx.x*2 + pair)*64;
    int row_ = rowBase + lane;
    bool active = row_ < N_ROWS;
    int row = active ? row_ : 0;
    int v = row / 12, p = row % 12;

    // conv contraction: h[k] = sum_o x1[v,o,k]*fk[p,o,k]
    float h[64];
    #pragma unroll
    for (int k = 0; k < 64; k++) h[k] = 0.f;
    const float* xv = x1 + (size_t)v*768;
    const float* fp = fk + (size_t)p*768;
    for (int o = 0; o < 12; o++) {
        const float4* xa = (const float4*)(xv + o*64);
        const float4* fa = (const float4*)(fp + o*64);
        #pragma unroll
        for (int k4 = 0; k4 < 16; k4++) {
            float4 xd = xa[k4]; float4 fd = fa[k4];
            h[4*k4+0] += xd.x*fd.x; h[4*k4+1] += xd.y*fd.y;
            h[4*k4+2] += xd.z*fd.z; h[4*k4+3] += xd.w*fd.w;
        }
    }
    const float inv12 = 1.0f/12.0f;
    float mu = 0.f;
    #pragma unroll
    for (int k = 0; k < 64; k++) { h[k] = h[k]*inv12 + conv_b[k]; mu += h[k]; }
    mu *= (1.0f/64.0f);
    float var = 0.f;
    #pragma unroll
    for (int k = 0; k < 64; k++) { float xc = h[k] - mu; var += xc*xc; }
    var *= (1.0f/64.0f);
    float rstd = rsqrtf(var + 1e-5f);
    #pragma unroll
    for (int k = 0; k < 64; k++) h[k] = (h[k] - mu)*rstd*ln_g[k] + ln_b[k];

    // half the hidden units per wave
    float outv[64];
    if (half == 0) {
        #pragma unroll
        for (int k = 0; k < 64; k++) outv[k] = b2[k];
    } else {
        #pragma unroll
        for (int k = 0; k < 64; k++) outv[k] = 0.f;
    }
    for (int ch = 0; ch < 8; ch++) {                 // 8 chunks of 16 t
        int tbase = half*128 + ch*16;
        float hid[16];
        #pragma unroll
        for (int j = 0; j < 16; j++) {
            int t = tbase + j;
            const float4* wr = (const float4*)(W1T + t*64);   // uniform -> s_load
            float a = b1[t];
            #pragma unroll
            for (int k4 = 0; k4 < 16; k4++) {
                float4 wv = wr[k4];
                a += h[4*k4]*wv.x + h[4*k4+1]*wv.y + h[4*k4+2]*wv.z + h[4*k4+3]*wv.w;
            }
            hid[j] = gelu_f(a);
        }
        #pragma unroll
        for (int c = 0; c < 64; c++) {
            const float4* w2r = (const float4*)(W2T + c*256 + tbase);  // uniform
            float a = 0.f;
            #pragma unroll
            for (int j4 = 0; j4 < 4; j4++) {
                float4 wv = w2r[j4];
                a += hid[4*j4]*wv.x + hid[4*j4+1]*wv.y + hid[4*j4+2]*wv.z + hid[4*j4+3]*wv.w;
            }
            outv[c] += a;
        }
    }

    // pair-reduce: wave1's partial -> LDS (stride 65: bank = (lane+c)%32, free)
    float* so = &sOut[pair][0];
    if (half == 1) {
        #pragma unroll
        for (int c = 0; c < 64; c++) so[lane*65 + c] = outv[c];
    }
    __syncthreads();
    if (half == 0) {
        #pragma unroll
        for (int c = 0; c < 64; c++) outv[c] += so[lane*65 + c];
        if (has_res) {
            const float* xo = x_old + (size_t)row*64;
            #pragma unroll
            for (int k = 0; k < 64; k++) outv[k] += xo[k];
        }
        if (active) {
            if (write_x) {
                float* xn = x_new + (size_t)row*64;
                #pragma unroll
                for (int k = 0; k < 64; k++) xn[k] = outv[k];
            }
            float r0 = br[0], r1 = br[1];
            #pragma unroll
            for (int k = 0; k < 64; k++) { r0 += outv[k]*Wr[2*k]; r1 += outv[k]*Wr[2*k+1]; }
            racc[row*2 + 0] += r0;
            racc[row*2 + 1] += r1;
        }
    }
}

// ---------------------------------------------------------------------------
// K6: readout
// ---------------------------------------------------------------------------
__global__ __launch_bounds__(256) void final_kernel(
    const float* __restrict__ racc, const float* __restrict__ ori,
    const int* __restrict__ batch, float* __restrict__ out)
{
    int v = blockIdx.x*256 + threadIdx.x;
    if (v >= N_NODES) return;
    float srs = 0.f, vx = 0.f, vy = 0.f, vz = 0.f;
    #pragma unroll
    for (int p = 0; p < 12; p++) {
        float r0 = racc[v*24 + 2*p], r1 = racc[v*24 + 2*p + 1];
        srs += r0;
        vx += r1*ori[3*p]; vy += r1*ori[3*p+1]; vz += r1*ori[3*p+2];
    }
    const float sc = 1.0f/24.0f;
    int g = batch[v];
    atomicAdd(&out[g], srs*sc);
    atomicAdd(&out[16 + g*3 + 0], vx*sc);
    atomicAdd(&out[16 + g*3 + 1], vy*sc);
    atomicAdd(&out[16 + g*3 + 2], vz*sc);
}

extern "C" void kernel_launch(void* const* d_in, const int* in_sizes, int n_in,
                              void* d_out, int out_size, void* d_ws, size_t ws_size,
                              hipStream_t stream) {
    const float* pos    = (const float*)d_in[0];
    const float* f      = (const float*)d_in[1];
    const float* ori    = (const float*)d_in[2];
    const int*   ei     = (const int*)  d_in[3];
    const int*   batch  = (const int*)  d_in[4];
    const float* Wb1    = (const float*)d_in[5];
    const float* bb1    = (const float*)d_in[6];
    const float* Wb2    = (const float*)d_in[7];
    const float* bb2    = (const float*)d_in[8];
    const float* Wo1    = (const float*)d_in[9];
    const float* bo1    = (const float*)d_in[10];
    const float* Wo2    = (const float*)d_in[11];
    const float* bo2    = (const float*)d_in[12];
    const float* We     = (const float*)d_in[13];
    const float* Wk     = (const float*)d_in[14];
    const float* Wf     = (const float*)d_in[15];
    const float* conv_b = (const float*)d_in[16];
    const float* ln_g   = (const float*)d_in[17];
    const float* ln_b   = (const float*)d_in[18];
    const float* W1     = (const float*)d_in[19];
    const float* b1     = (const float*)d_in[20];
    const float* W2     = (const float*)d_in[21];
    const float* b2     = (const float*)d_in[22];
    const float* Wr     = (const float*)d_in[23];
    const float* br     = (const float*)d_in[24];
    float* out = (float*)d_out;

    float* ws   = (float*)d_ws;
    float* xe   = ws;                       //   640,000 f32
    float* xs1  = xe   + 640000;            // 7,680,000
    float* x1a  = xs1  + 7680000;           // 7,680,000
    float* racc = x1a  + 7680000;           //   240,000
    float* fkb  = racc + 240000;            //    18,432
    float* w1t  = fkb  + 18432;             //    32,768 (2 layers)
    float* w2t  = w1t  + 32768;             //    32,768
    __hip_bfloat16* kbb = (__hip_bfloat16*)(w2t + 32768);   // 61,440,000 bf16 (~123 MB)

    hipMemsetAsync(out,  0, 64*sizeof(float), stream);
    hipMemsetAsync(racc, 0, 240000*sizeof(float), stream);
    hipMemsetAsync(x1a,  0, 7680000*sizeof(float), stream);

    transpose_w <<<2,    256, 0, stream>>>(W1, W2, w1t, w2t);
    ori_kernel  <<<144,  64, 0, stream>>>(ori, Wo1, bo1, Wo2, bo2, Wf, fkb);
    embed_kernel<<<2500, 256, 0, stream>>>(f, We, xe);
    kb_kernel   <<<20000,256, 0, stream>>>(pos, ori, Wb1, bb1, Wb2, bb2, ei, kbb);

    // layer 0
    scatter_kernel<<<20000,256, 0, stream>>>(kbb, Wk, ei, xe, x1a, /*has_ori=*/0);
    node_kernel   <<<938,  256, 0, stream>>>(x1a, fkb, conv_b, ln_g, ln_b,
                                             w1t, b1, w2t, b2, Wr, br,
                                             nullptr, xs1, racc, /*res=*/0, /*write=*/1);
    // layer 1
    hipMemsetAsync(x1a, 0, 7680000*sizeof(float), stream);
    scatter_kernel<<<20000,256, 0, stream>>>(kbb, Wk + 4096, ei, xs1, x1a, /*has_ori=*/1);
    node_kernel   <<<938,  256, 0, stream>>>(x1a, fkb + 9216, conv_b + 64, ln_g + 64, ln_b + 64,
                                             w1t + 16384, b1 + 256, w2t + 16384, b2 + 64,
                                             Wr + 128, br + 2,
                                             xs1, nullptr, racc, /*res=*/1, /*write=*/0);

    final_kernel<<<40,   256, 0, stream>>>(racc, ori, batch, out);
}

// Round 4
// 1532.392 us; speedup vs baseline: 1.3919x; 1.3919x over previous
//
#include <hip/hip_runtime.h>
#include <hip/hip_bf16.h>
#include <math.h>

#define N_NODES 10000
#define N_EDGES 80000
#define N_ORI   12
#define N_ROWS  (N_NODES * N_ORI)

typedef __attribute__((ext_vector_type(8))) short bfrag;   // 8 bf16 = 4 VGPRs
typedef __attribute__((ext_vector_type(4))) float f32x4;

__device__ __forceinline__ float gelu_f(float x) {
    return 0.5f * x * (1.0f + erff(x * 0.70710678118654752440f));
}
__device__ __forceinline__ short f2bf(float x) {
    __hip_bfloat16 h = __float2bfloat16(x);
    return *reinterpret_cast<short*>(&h);
}

// ---------------------------------------------------------------------------
// K0: weights -> bf16 fragment-friendly layouts.
// W1B[l][n=t][k]   (256x64)  from W1[l][k][t]
// W2B[l][n=c][k=t] (64x256)  from W2[l][t][c]
// ---------------------------------------------------------------------------
__global__ __launch_bounds__(256) void prep_weights(
    const float* __restrict__ W1, const float* __restrict__ W2,
    short* __restrict__ W1B, short* __restrict__ W2B)
{
    int l = blockIdx.x;
    const float* w1 = W1 + l*16384; short* w1b = W1B + l*16384;
    const float* w2 = W2 + l*16384; short* w2b = W2B + l*16384;
    for (int i = threadIdx.x; i < 16384; i += 256) {
        int k = i >> 8, t = i & 255;          // W1[k][t]
        w1b[t*64 + k] = f2bf(w1[i]);
        int t2 = i >> 6, c = i & 63;          // W2[t][c]
        w2b[c*256 + t2] = f2bf(w2[i]);
    }
}

// ---------------------------------------------------------------------------
// K1: kb_ori MLP + fk[l][p][o][c] = (kb_ori @ Wf[l]).
// ---------------------------------------------------------------------------
__global__ __launch_bounds__(64) void ori_kernel(
    const float* __restrict__ ori, const float* __restrict__ Wo1,
    const float* __restrict__ bo1, const float* __restrict__ Wo2,
    const float* __restrict__ bo2, const float* __restrict__ Wf,
    float* __restrict__ fkb)
{
    __shared__ float sh[64];
    __shared__ float skb[64];
    int i = blockIdx.x / 12, j = blockIdx.x % 12;
    int lane = threadIdx.x;
    float s = ori[3*i]*ori[3*j] + ori[3*i+1]*ori[3*j+1] + ori[3*i+2]*ori[3*j+2];
    float p1 = s, p2 = s*s, p3 = p2*s, p4 = p3*s;
    float acc = bo1[lane] + p1*Wo1[lane] + p2*Wo1[64+lane] + p3*Wo1[128+lane] + p4*Wo1[192+lane];
    sh[lane] = gelu_f(acc);
    __syncthreads();
    float acc2 = bo2[lane];
    #pragma unroll
    for (int k = 0; k < 64; k++) acc2 += sh[k] * Wo2[k*64 + lane];
    skb[lane] = gelu_f(acc2);
    __syncthreads();
    for (int l = 0; l < 2; l++) {
        float a = 0.f;
        #pragma unroll
        for (int k = 0; k < 64; k++) a += skb[k] * Wf[l*4096 + k*64 + lane];
        fkb[l*9216 + i*768 + j*64 + lane] = a;
    }
}

// ---------------------------------------------------------------------------
// K2: x = f @ We
// ---------------------------------------------------------------------------
__global__ __launch_bounds__(256) void embed_kernel(
    const float* __restrict__ f, const float* __restrict__ We, float* __restrict__ xe)
{
    int v = blockIdx.x*4 + (threadIdx.x >> 6);
    int lane = threadIdx.x & 63;
    if (v >= N_NODES) return;
    float acc = 0.f;
    #pragma unroll
    for (int k = 0; k < 16; k++) acc += f[v*16 + k] * We[k*64 + lane];
    xe[v*64 + lane] = acc;
}

// ---------------------------------------------------------------------------
// K3: kb[e,o,c] bf16, once. (unchanged from round 2/3 — known good)
// ---------------------------------------------------------------------------
__global__ __launch_bounds__(256) void kb_kernel(
    const float* __restrict__ pos, const float* __restrict__ ori,
    const float* __restrict__ Wb1, const float* __restrict__ bb1,
    const float* __restrict__ Wb2, const float* __restrict__ bb2,
    const int* __restrict__ ei, __hip_bfloat16* __restrict__ kbb)
{
    __shared__ float sh1[4][64];
    int w = threadIdx.x >> 6, lane = threadIdx.x & 63;

    float wb1c[30], wb2c[64];
    #pragma unroll
    for (int k = 0; k < 30; k++) wb1c[k] = Wb1[k*64 + lane];
    #pragma unroll
    for (int k = 0; k < 64; k++) wb2c[k] = Wb2[k*64 + lane];
    float bb1l = bb1[lane], bb2l = bb2[lane];

    int e  = blockIdx.x*4 + w;
    int sn = ei[e], dn = ei[N_EDGES + e];
    float rx = pos[sn*3+0] - pos[dn*3+0];
    float ry = pos[sn*3+1] - pos[dn*3+1];
    float rz = pos[sn*3+2] - pos[dn*3+2];
    float d  = sqrtf(rx*rx + ry*ry + rz*rz);
    float u2 = d*d, u4 = u2*u2, u6 = u4*u2;
    float env = (d < 1.0f) ? (1.0f - 28.0f*u6 + 48.0f*u6*d - 21.0f*u6*u2) : 0.0f;
    __hip_bfloat16* kbrow = kbb + (size_t)e*768;

    for (int o = 0; o < N_ORI; o++) {
        float ox = ori[3*o], oy = ori[3*o+1], oz = ori[3*o+2];
        float a  = rx*ox + ry*oy + rz*oz;
        float qx = rx - a*ox, qy = ry - a*oy, qz = rz - a*oz;
        float b  = sqrtf(qx*qx + qy*qy + qz*qz);
        float acc = bb1l + a*wb1c[0] + b*wb1c[1];
        float c0 = a*a, c1 = a*b, c2 = b*a, c3 = b*b;
        acc += c0*wb1c[2] + c1*wb1c[3] + c2*wb1c[4] + c3*wb1c[5];
        float d0=c0*a,d1=c0*b,d2=c1*a,d3=c1*b,d4=c2*a,d5=c2*b,d6=c3*a,d7=c3*b;
        acc += d0*wb1c[6]+d1*wb1c[7]+d2*wb1c[8]+d3*wb1c[9]
             + d4*wb1c[10]+d5*wb1c[11]+d6*wb1c[12]+d7*wb1c[13];
        acc += d0*a*wb1c[14]+d0*b*wb1c[15]+d1*a*wb1c[16]+d1*b*wb1c[17]
             + d2*a*wb1c[18]+d2*b*wb1c[19]+d3*a*wb1c[20]+d3*b*wb1c[21]
             + d4*a*wb1c[22]+d4*b*wb1c[23]+d5*a*wb1c[24]+d5*b*wb1c[25]
             + d6*a*wb1c[26]+d6*b*wb1c[27]+d7*a*wb1c[28]+d7*b*wb1c[29];
        sh1[w][lane] = gelu_f(acc);
        __builtin_amdgcn_wave_barrier();
        float acc2 = bb2l;
        const float4* h4 = (const float4*)(&sh1[w][0]);
        #pragma unroll
        for (int k4 = 0; k4 < 16; k4++) {
            float4 hv = h4[k4];
            acc2 += hv.x*wb2c[4*k4] + hv.y*wb2c[4*k4+1] + hv.z*wb2c[4*k4+2] + hv.w*wb2c[4*k4+3];
        }
        __builtin_amdgcn_wave_barrier();
        kbrow[o*64 + lane] = __float2bfloat16(gelu_f(acc2) * env);
    }
}

// ---------------------------------------------------------------------------
// K4: per-layer scatter (unchanged)
// ---------------------------------------------------------------------------
__global__ __launch_bounds__(256) void scatter_kernel(
    const __hip_bfloat16* __restrict__ kbb, const float* __restrict__ Wk,
    const int* __restrict__ ei, const float* __restrict__ x_in,
    float* __restrict__ x1, int has_ori)
{
    __shared__ float skb[4][64];
    int w = threadIdx.x >> 6, lane = threadIdx.x & 63;
    float wkc[64];
    #pragma unroll
    for (int k = 0; k < 64; k++) wkc[k] = Wk[k*64 + lane];

    int e  = blockIdx.x*4 + w;
    int sn = ei[e], dn = ei[N_EDGES + e];
    const __hip_bfloat16* kbrow = kbb + (size_t)e*768;
    const float* xsrc  = x_in + (has_ori ? (size_t)sn*768 : (size_t)sn*64);
    float*       x1row = x1 + (size_t)dn*768;
    float xs0 = has_ori ? 0.f : xsrc[lane];

    for (int o = 0; o < N_ORI; o++) {
        skb[w][lane] = __bfloat162float(kbrow[o*64 + lane]);
        __builtin_amdgcn_wave_barrier();
        float accm = 0.f;
        const float4* kb4 = (const float4*)(&skb[w][0]);
        #pragma unroll
        for (int k4 = 0; k4 < 16; k4++) {
            float4 kv = kb4[k4];
            accm += kv.x*wkc[4*k4] + kv.y*wkc[4*k4+1] + kv.z*wkc[4*k4+2] + kv.w*wkc[4*k4+3];
        }
        __builtin_amdgcn_wave_barrier();
        float xs = has_ori ? xsrc[o*64 + lane] : xs0;
        atomicAdd(&x1row[o*64 + lane], xs * accm);
    }
}

// ---------------------------------------------------------------------------
// K5 (NEW): MFMA node kernel. 128 rows/block, 4 waves.
// Phase A (VALU): conv + LN -> bf16 A1 tile in LDS.
// Phase B/C (MFMA 16x16x32 bf16): FFN1 (K=64) -> gelu -> A2 half-tiles ->
// FFN2 (K=256, accumulated over two halves). Wave w owns mtiles {2w,2w+1}.
// Epilogue (f32): +b2, +residual, write x_new, readout shuffle-reduce -> racc.
// LDS = 18.4K + 34.8K = 53.2 KB -> 2 blocks/CU.
// ---------------------------------------------------------------------------
__global__ __launch_bounds__(256, 2) void node_mfma(
    const float* __restrict__ x1, const float* __restrict__ fk,
    const float* __restrict__ conv_b, const float* __restrict__ ln_g,
    const float* __restrict__ ln_b,
    const short* __restrict__ W1B, const float* __restrict__ b1,
    const short* __restrict__ W2B, const float* __restrict__ pb2,
    const float* __restrict__ Wr, const float* __restrict__ br,
    const float* __restrict__ x_old, float* __restrict__ x_new,
    float* __restrict__ racc, int has_res, int write_x)
{
    __shared__ short sA1[128*72];    // [row][k0..63], stride 72 (144B, 16B-aligned)
    __shared__ short sA2[128*136];   // [row][t-half 0..127], stride 136 (272B)

    int tid = threadIdx.x;
    int blockRow = blockIdx.x * 128;

    // ---- Phase A: conv + LN -> sA1 bf16 ----
    {
        int rl = tid >> 1, hf = tid & 1;
        int row = blockRow + rl;
        int rc = row < N_ROWS ? row : N_ROWS - 1;
        int v = rc / 12, pp = rc % 12;
        float h[32];
        #pragma unroll
        for (int k = 0; k < 32; k++) h[k] = 0.f;
        const float* xv = x1 + (size_t)v*768 + hf*32;
        const float* fp = fk + (size_t)pp*768 + hf*32;
        for (int o = 0; o < 12; o++) {
            const float4* xa = (const float4*)(xv + o*64);
            const float4* fa = (const float4*)(fp + o*64);
            #pragma unroll
            for (int k4 = 0; k4 < 8; k4++) {
                float4 xd = xa[k4]; float4 fd = fa[k4];
                h[4*k4+0] += xd.x*fd.x; h[4*k4+1] += xd.y*fd.y;
                h[4*k4+2] += xd.z*fd.z; h[4*k4+3] += xd.w*fd.w;
            }
        }
        const float inv12 = 1.0f/12.0f;
        float sum = 0.f;
        #pragma unroll
        for (int k = 0; k < 32; k++) { h[k] = h[k]*inv12 + conv_b[hf*32 + k]; sum += h[k]; }
        sum += __shfl_xor(sum, 1);
        float mu = sum * (1.0f/64.0f);
        float var = 0.f;
        #pragma unroll
        for (int k = 0; k < 32; k++) { float xc = h[k] - mu; var += xc*xc; }
        var += __shfl_xor(var, 1);
        float rstd = rsqrtf(var*(1.0f/64.0f) + 1e-5f);
        short* dst = sA1 + rl*72 + hf*32;
        #pragma unroll
        for (int blk = 0; blk < 4; blk++) {
            union { short s[8]; int4 v4; } u;
            #pragma unroll
            for (int j = 0; j < 8; j++) {
                int k = blk*8 + j, c = hf*32 + k;
                u.s[j] = f2bf((h[k] - mu)*rstd*ln_g[c] + ln_b[c]);
            }
            *(int4*)(dst + blk*8) = u.v4;
        }
    }
    __syncthreads();

    int w   = tid >> 6;
    int l   = tid & 63;
    int m16 = l & 15, q = l >> 4;

    // Hoist A1 fragments: 2 mtiles x 2 k-chunks
    bfrag a1[2][2];
    #pragma unroll
    for (int i = 0; i < 2; i++) {
        int mt = 2*w + i;
        #pragma unroll
        for (int kc = 0; kc < 2; kc++)
            a1[i][kc] = *(const bfrag*)(sA1 + (mt*16 + m16)*72 + kc*32 + q*8);
    }

    f32x4 acc2[4][2];   // [ntile c][mtile i]
    #pragma unroll
    for (int n = 0; n < 4; n++)
        #pragma unroll
        for (int i = 0; i < 2; i++)
            acc2[n][i] = (f32x4){0.f, 0.f, 0.f, 0.f};

    for (int ph = 0; ph < 2; ph++) {
        // ---- FFN1: ntiles [ph*8, ph*8+8) -> gelu -> sA2 ----
        for (int ntl = 0; ntl < 8; ntl++) {
            int nt = ph*8 + ntl;
            f32x4 c0 = (f32x4){0.f,0.f,0.f,0.f};
            f32x4 c1 = (f32x4){0.f,0.f,0.f,0.f};
            #pragma unroll
            for (int kc = 0; kc < 2; kc++) {
                bfrag bb = *(const bfrag*)(W1B + (nt*16 + m16)*64 + kc*32 + q*8);
                c0 = __builtin_amdgcn_mfma_f32_16x16x32_bf16(a1[0][kc], bb, c0, 0, 0, 0);
                c1 = __builtin_amdgcn_mfma_f32_16x16x32_bf16(a1[1][kc], bb, c1, 0, 0, 0);
            }
            float bias = b1[nt*16 + m16];
            #pragma unroll
            for (int r = 0; r < 4; r++) {
                int r0 = (2*w)*16 + q*4 + r;
                int r1 = (2*w+1)*16 + q*4 + r;
                sA2[r0*136 + ntl*16 + m16] = f2bf(gelu_f(c0[r] + bias));
                sA2[r1*136 + ntl*16 + m16] = f2bf(gelu_f(c1[r] + bias));
            }
        }
        __syncthreads();
        // ---- FFN2 partial: K-chunks of this half ----
        for (int kc2 = 0; kc2 < 4; kc2++) {
            bfrag a2[2];
            #pragma unroll
            for (int i = 0; i < 2; i++)
                a2[i] = *(const bfrag*)(sA2 + ((2*w+i)*16 + m16)*136 + kc2*32 + q*8);
            #pragma unroll
            for (int nc = 0; nc < 4; nc++) {
                bfrag bb = *(const bfrag*)(W2B + (nc*16 + m16)*256 + ph*128 + kc2*32 + q*8);
                acc2[nc][0] = __builtin_amdgcn_mfma_f32_16x16x32_bf16(a2[0], bb, acc2[nc][0], 0, 0, 0);
                acc2[nc][1] = __builtin_amdgcn_mfma_f32_16x16x32_bf16(a2[1], bb, acc2[nc][1], 0, 0, 0);
            }
        }
        __syncthreads();   // before overwriting sA2 next half
    }

    // ---- Epilogue: bias, residual, store x_new, readout reduce -> racc ----
    float p0[2][4], p1[2][4];
    #pragma unroll
    for (int i = 0; i < 2; i++) {
        #pragma unroll
        for (int r = 0; r < 4; r++) {
            int rowl = (2*w+i)*16 + q*4 + r;
            int row  = blockRow + rowl;
            bool ok  = row < N_ROWS;
            float vals[4];
            #pragma unroll
            for (int nc = 0; nc < 4; nc++) vals[nc] = acc2[nc][i][r] + pb2[nc*16 + m16];
            if (has_res && ok) {
                #pragma unroll
                for (int nc = 0; nc < 4; nc++) vals[nc] += x_old[(size_t)row*64 + nc*16 + m16];
            }
            if (write_x && ok) {
                #pragma unroll
                for (int nc = 0; nc < 4; nc++) x_new[(size_t)row*64 + nc*16 + m16] = vals[nc];
            }
            float q0 = 0.f, q1 = 0.f;
            #pragma unroll
            for (int nc = 0; nc < 4; nc++) {
                int c = nc*16 + m16;
                q0 += vals[nc]*Wr[2*c];
                q1 += vals[nc]*Wr[2*c + 1];
            }
            p0[i][r] = q0; p1[i][r] = q1;
        }
    }
    #pragma unroll
    for (int s = 1; s < 16; s <<= 1) {
        #pragma unroll
        for (int i = 0; i < 2; i++)
            #pragma unroll
            for (int r = 0; r < 4; r++) {
                p0[i][r] += __shfl_xor(p0[i][r], s);
                p1[i][r] += __shfl_xor(p1[i][r], s);
            }
    }
    if (m16 == 0) {
        #pragma unroll
        for (int i = 0; i < 2; i++)
            #pragma unroll
            for (int r = 0; r < 4; r++) {
                int row = blockRow + (2*w+i)*16 + q*4 + r;
                if (row < N_ROWS) {
                    atomicAdd(&racc[row*2 + 0], p0[i][r] + br[0]);
                    atomicAdd(&racc[row*2 + 1], p1[i][r] + br[1]);
                }
            }
    }
}

// ---------------------------------------------------------------------------
// K6: readout
// ---------------------------------------------------------------------------
__global__ __launch_bounds__(256) void final_kernel(
    const float* __restrict__ racc, const float* __restrict__ ori,
    const int* __restrict__ batch, float* __restrict__ out)
{
    int v = blockIdx.x*256 + threadIdx.x;
    if (v >= N_NODES) return;
    float srs = 0.f, vx = 0.f, vy = 0.f, vz = 0.f;
    #pragma unroll
    for (int p = 0; p < 12; p++) {
        float r0 = racc[v*24 + 2*p], r1 = racc[v*24 + 2*p + 1];
        srs += r0;
        vx += r1*ori[3*p]; vy += r1*ori[3*p+1]; vz += r1*ori[3*p+2];
    }
    const float sc = 1.0f/24.0f;
    int g = batch[v];
    atomicAdd(&out[g], srs*sc);
    atomicAdd(&out[16 + g*3 + 0], vx*sc);
    atomicAdd(&out[16 + g*3 + 1], vy*sc);
    atomicAdd(&out[16 + g*3 + 2], vz*sc);
}

extern "C" void kernel_launch(void* const* d_in, const int* in_sizes, int n_in,
                              void* d_out, int out_size, void* d_ws, size_t ws_size,
                              hipStream_t stream) {
    const float* pos    = (const float*)d_in[0];
    const float* f      = (const float*)d_in[1];
    const float* ori    = (const float*)d_in[2];
    const int*   ei     = (const int*)  d_in[3];
    const int*   batch  = (const int*)  d_in[4];
    const float* Wb1    = (const float*)d_in[5];
    const float* bb1    = (const float*)d_in[6];
    const float* Wb2    = (const float*)d_in[7];
    const float* bb2    = (const float*)d_in[8];
    const float* Wo1    = (const float*)d_in[9];
    const float* bo1    = (const float*)d_in[10];
    const float* Wo2    = (const float*)d_in[11];
    const float* bo2    = (const float*)d_in[12];
    const float* We     = (const float*)d_in[13];
    const float* Wk     = (const float*)d_in[14];
    const float* Wf     = (const float*)d_in[15];
    const float* conv_b = (const float*)d_in[16];
    const float* ln_g   = (const float*)d_in[17];
    const float* ln_b   = (const float*)d_in[18];
    const float* W1     = (const float*)d_in[19];
    const float* b1     = (const float*)d_in[20];
    const float* W2     = (const float*)d_in[21];
    const float* b2     = (const float*)d_in[22];
    const float* Wr     = (const float*)d_in[23];
    const float* br     = (const float*)d_in[24];
    float* out = (float*)d_out;

    float* ws   = (float*)d_ws;
    float* xe   = ws;                       //   640,000 f32
    float* xs1  = xe   + 640000;            // 7,680,000
    float* x1a  = xs1  + 7680000;           // 7,680,000
    float* racc = x1a  + 7680000;           //   240,000
    float* fkb  = racc + 240000;            //    18,432
    short* w1b  = (short*)(fkb + 18432);    //    32,768 shorts (2 layers)
    short* w2b  = w1b + 32768;              //    32,768 shorts
    __hip_bfloat16* kbb = (__hip_bfloat16*)(w2b + 32768);   // 61,440,000 bf16

    hipMemsetAsync(out,  0, 64*sizeof(float), stream);
    hipMemsetAsync(racc, 0, 240000*sizeof(float), stream);
    hipMemsetAsync(x1a,  0, 7680000*sizeof(float), stream);

    prep_weights<<<2,    256, 0, stream>>>(W1, W2, w1b, w2b);
    ori_kernel  <<<144,  64, 0, stream>>>(ori, Wo1, bo1, Wo2, bo2, Wf, fkb);
    embed_kernel<<<2500, 256, 0, stream>>>(f, We, xe);
    kb_kernel   <<<20000,256, 0, stream>>>(pos, ori, Wb1, bb1, Wb2, bb2, ei, kbb);

    // layer 0
    scatter_kernel<<<20000,256, 0, stream>>>(kbb, Wk, ei, xe, x1a, /*has_ori=*/0);
    node_mfma     <<<938,  256, 0, stream>>>(x1a, fkb, conv_b, ln_g, ln_b,
                                             w1b, b1, w2b, b2, Wr, br,
                                             xs1, xs1, racc, /*res=*/0, /*write=*/1);
    // layer 1
    hipMemsetAsync(x1a, 0, 7680000*sizeof(float), stream);
    scatter_kernel<<<20000,256, 0, stream>>>(kbb, Wk + 4096, ei, xs1, x1a, /*has_ori=*/1);
    node_mfma     <<<938,  256, 0, stream>>>(x1a, fkb + 9216, conv_b + 64, ln_g + 64, ln_b + 64,
                                             w1b + 16384, b1 + 256, w2b + 16384, b2 + 64,
                                             Wr + 128, br + 2,
                                             xs1, xs1, racc, /*res=*/1, /*write=*/0);

    final_kernel<<<40,   256, 0, stream>>>(racc, ori, batch, out);
}

// Round 5
// 1331.934 us; speedup vs baseline: 1.6014x; 1.1505x over previous
//
#include <hip/hip_runtime.h>
#include <hip/hip_bf16.h>
#include <math.h>

#define N_NODES 10000
#define N_EDGES 80000
#define N_ORI   12
#define N_ROWS  (N_NODES * N_ORI)
#define N_EROWS (N_EDGES * N_ORI)

typedef __attribute__((ext_vector_type(8))) short bfrag;   // 8 bf16 = 4 VGPRs
typedef __attribute__((ext_vector_type(4))) float f32x4;

__device__ __forceinline__ float gelu_f(float x) {
    return 0.5f * x * (1.0f + erff(x * 0.70710678118654752440f));
}
__device__ __forceinline__ short f2bf(float x) {
    __hip_bfloat16 h = __float2bfloat16(x);
    return *reinterpret_cast<short*>(&h);
}

// ---------------------------------------------------------------------------
// K0: weight prep.
// blocks 0,1 (l=0,1): W1B[l][t][k] (256x64) from W1[l][k][t];
//                     W2B[l][c][t] (64x256) from W2[l][t][c]
// block 2:            W1K[t][k0..31] (64x32, k>=30 zero) from Wb1[k][t];
//                     W2K[c][t] (64x64) from Wb2[t][c]
// ---------------------------------------------------------------------------
__global__ __launch_bounds__(256) void prep_weights(
    const float* __restrict__ W1, const float* __restrict__ W2,
    const float* __restrict__ Wb1, const float* __restrict__ Wb2,
    short* __restrict__ W1B, short* __restrict__ W2B,
    short* __restrict__ W1K, short* __restrict__ W2K)
{
    if (blockIdx.x < 2) {
        int l = blockIdx.x;
        const float* w1 = W1 + l*16384; short* w1b = W1B + l*16384;
        const float* w2 = W2 + l*16384; short* w2b = W2B + l*16384;
        for (int i = threadIdx.x; i < 16384; i += 256) {
            int k = i >> 8, t = i & 255;          // W1[k][t]
            w1b[t*64 + k] = f2bf(w1[i]);
            int t2 = i >> 6, c = i & 63;          // W2[t][c]
            w2b[c*256 + t2] = f2bf(w2[i]);
        }
    } else {
        for (int i = threadIdx.x; i < 2048; i += 256) {
            int t = i >> 5, k = i & 31;
            W1K[i] = (k < 30) ? f2bf(Wb1[k*64 + t]) : (short)0;
        }
        for (int i = threadIdx.x; i < 4096; i += 256) {
            int c = i >> 6, t = i & 63;
            W2K[i] = f2bf(Wb2[t*64 + c]);
        }
    }
}

// ---------------------------------------------------------------------------
// K1: kb_ori MLP + fk[l][p][o][c] = (kb_ori @ Wf[l]).
// ---------------------------------------------------------------------------
__global__ __launch_bounds__(64) void ori_kernel(
    const float* __restrict__ ori, const float* __restrict__ Wo1,
    const float* __restrict__ bo1, const float* __restrict__ Wo2,
    const float* __restrict__ bo2, const float* __restrict__ Wf,
    float* __restrict__ fkb)
{
    __shared__ float sh[64];
    __shared__ float skb[64];
    int i = blockIdx.x / 12, j = blockIdx.x % 12;
    int lane = threadIdx.x;
    float s = ori[3*i]*ori[3*j] + ori[3*i+1]*ori[3*j+1] + ori[3*i+2]*ori[3*j+2];
    float p1 = s, p2 = s*s, p3 = p2*s, p4 = p3*s;
    float acc = bo1[lane] + p1*Wo1[lane] + p2*Wo1[64+lane] + p3*Wo1[128+lane] + p4*Wo1[192+lane];
    sh[lane] = gelu_f(acc);
    __syncthreads();
    float acc2 = bo2[lane];
    #pragma unroll
    for (int k = 0; k < 64; k++) acc2 += sh[k] * Wo2[k*64 + lane];
    skb[lane] = gelu_f(acc2);
    __syncthreads();
    for (int l = 0; l < 2; l++) {
        float a = 0.f;
        #pragma unroll
        for (int k = 0; k < 64; k++) a += skb[k] * Wf[l*4096 + k*64 + lane];
        fkb[l*9216 + i*768 + j*64 + lane] = a;
    }
}

// ---------------------------------------------------------------------------
// K2: x = f @ We
// ---------------------------------------------------------------------------
__global__ __launch_bounds__(256) void embed_kernel(
    const float* __restrict__ f, const float* __restrict__ We, float* __restrict__ xe)
{
    int v = blockIdx.x*4 + (threadIdx.x >> 6);
    int lane = threadIdx.x & 63;
    if (v >= N_NODES) return;
    float acc = 0.f;
    #pragma unroll
    for (int k = 0; k < 16; k++) acc += f[v*16 + k] * We[k*64 + lane];
    xe[v*64 + lane] = acc;
}

// ---------------------------------------------------------------------------
// K3 (NEW): kb via MFMA. 256 (e,o) rows/block, grid 3750 (exact cover).
// Phase A (VALU): per-thread row features (poly30, bf16) -> sF stride 40.
// FFN1: [256x32]@[32x64] MFMA (K padded) -> gelu -> sH stride 72.
// FFN2: [256x64]@[64x64] MFMA -> gelu * env -> kb bf16.
// LDS = 20.5K + 36.9K + 1K = 58.4 KB -> 2 blocks/CU.
// ---------------------------------------------------------------------------
__global__ __launch_bounds__(256, 2) void kb_mfma(
    const float* __restrict__ pos, const float* __restrict__ ori,
    const short* __restrict__ W1K, const float* __restrict__ bb1,
    const short* __restrict__ W2K, const float* __restrict__ bb2,
    const int* __restrict__ ei, __hip_bfloat16* __restrict__ kbb)
{
    __shared__ short sF[256*40];
    __shared__ short sH[256*72];
    __shared__ float sEnv[256];

    int tid = threadIdx.x;
    int blockRow = blockIdx.x * 256;

    // ---- Phase A: features ----
    {
        int row = blockRow + tid;
        int e = row / 12, o = row - e*12;
        int sn = ei[e], dn = ei[N_EDGES + e];
        float rx = pos[sn*3+0] - pos[dn*3+0];
        float ry = pos[sn*3+1] - pos[dn*3+1];
        float rz = pos[sn*3+2] - pos[dn*3+2];
        float d  = sqrtf(rx*rx + ry*ry + rz*rz);
        float u2 = d*d, u4 = u2*u2, u6 = u4*u2;
        float env = (d < 1.0f) ? (1.0f - 28.0f*u6 + 48.0f*u6*d - 21.0f*u6*u2) : 0.0f;
        sEnv[tid] = env;

        float ox = ori[3*o], oy = ori[3*o+1], oz = ori[3*o+2];
        float a  = rx*ox + ry*oy + rz*oz;
        float qx = rx - a*ox, qy = ry - a*oy, qz = rz - a*oz;
        float b  = sqrtf(qx*qx + qy*qy + qz*qz);

        float fv[32];
        fv[0] = a; fv[1] = b;
        fv[2] = a*a; fv[3] = a*b; fv[4] = b*a; fv[5] = b*b;
        #pragma unroll
        for (int i = 0; i < 4; i++) { fv[6+2*i] = fv[2+i]*a; fv[7+2*i] = fv[2+i]*b; }
        #pragma unroll
        for (int i = 0; i < 8; i++) { fv[14+2*i] = fv[6+i]*a; fv[15+2*i] = fv[6+i]*b; }
        fv[30] = 0.f; fv[31] = 0.f;

        short* dst = sF + tid*40;
        #pragma unroll
        for (int blk = 0; blk < 4; blk++) {
            union { short s[8]; int4 v4; } u;
            #pragma unroll
            for (int j = 0; j < 8; j++) u.s[j] = f2bf(fv[blk*8 + j]);
            *(int4*)(dst + blk*8) = u.v4;
        }
    }
    __syncthreads();

    int w = tid >> 6, l = tid & 63;
    int m16 = l & 15, q = l >> 4;

    // ---- FFN1: K=32, 4 mtiles/wave x 4 ntiles ----
    bfrag a1[4];
    #pragma unroll
    for (int mt = 0; mt < 4; mt++)
        a1[mt] = *(const bfrag*)(sF + ((w*4 + mt)*16 + m16)*40 + q*8);

    #pragma unroll
    for (int nt = 0; nt < 4; nt++) {
        bfrag bb = *(const bfrag*)(W1K + (nt*16 + m16)*32 + q*8);
        float bias = bb1[nt*16 + m16];
        #pragma unroll
        for (int mt = 0; mt < 4; mt++) {
            f32x4 acc = (f32x4){0.f,0.f,0.f,0.f};
            acc = __builtin_amdgcn_mfma_f32_16x16x32_bf16(a1[mt], bb, acc, 0, 0, 0);
            #pragma unroll
            for (int r = 0; r < 4; r++) {
                int rl = (w*4 + mt)*16 + q*4 + r;
                sH[rl*72 + nt*16 + m16] = f2bf(gelu_f(acc[r] + bias));
            }
        }
    }
    __syncthreads();

    // ---- FFN2: K=64 (2 ksteps) ----
    bfrag a2[4][2];
    #pragma unroll
    for (int mt = 0; mt < 4; mt++)
        #pragma unroll
        for (int kc = 0; kc < 2; kc++)
            a2[mt][kc] = *(const bfrag*)(sH + ((w*4 + mt)*16 + m16)*72 + kc*32 + q*8);

    #pragma unroll
    for (int nt = 0; nt < 4; nt++) {
        f32x4 acc[4];
        #pragma unroll
        for (int mt = 0; mt < 4; mt++) acc[mt] = (f32x4){0.f,0.f,0.f,0.f};
        #pragma unroll
        for (int kc = 0; kc < 2; kc++) {
            bfrag bb = *(const bfrag*)(W2K + (nt*16 + m16)*64 + kc*32 + q*8);
            #pragma unroll
            for (int mt = 0; mt < 4; mt++)
                acc[mt] = __builtin_amdgcn_mfma_f32_16x16x32_bf16(a2[mt][kc], bb, acc[mt], 0, 0, 0);
        }
        float bias = bb2[nt*16 + m16];
        #pragma unroll
        for (int mt = 0; mt < 4; mt++) {
            #pragma unroll
            for (int r = 0; r < 4; r++) {
                int rl = (w*4 + mt)*16 + q*4 + r;
                float val = gelu_f(acc[mt][r] + bias) * sEnv[rl];
                kbb[(size_t)(blockRow + rl)*64 + nt*16 + m16] = __float2bfloat16(val);
            }
        }
    }
}

// ---------------------------------------------------------------------------
// K4: per-layer scatter (unchanged)
// ---------------------------------------------------------------------------
__global__ __launch_bounds__(256) void scatter_kernel(
    const __hip_bfloat16* __restrict__ kbb, const float* __restrict__ Wk,
    const int* __restrict__ ei, const float* __restrict__ x_in,
    float* __restrict__ x1, int has_ori)
{
    __shared__ float skb[4][64];
    int w = threadIdx.x >> 6, lane = threadIdx.x & 63;
    float wkc[64];
    #pragma unroll
    for (int k = 0; k < 64; k++) wkc[k] = Wk[k*64 + lane];

    int e  = blockIdx.x*4 + w;
    int sn = ei[e], dn = ei[N_EDGES + e];
    const __hip_bfloat16* kbrow = kbb + (size_t)e*768;
    const float* xsrc  = x_in + (has_ori ? (size_t)sn*768 : (size_t)sn*64);
    float*       x1row = x1 + (size_t)dn*768;
    float xs0 = has_ori ? 0.f : xsrc[lane];

    for (int o = 0; o < N_ORI; o++) {
        skb[w][lane] = __bfloat162float(kbrow[o*64 + lane]);
        __builtin_amdgcn_wave_barrier();
        float accm = 0.f;
        const float4* kb4 = (const float4*)(&skb[w][0]);
        #pragma unroll
        for (int k4 = 0; k4 < 16; k4++) {
            float4 kv = kb4[k4];
            accm += kv.x*wkc[4*k4] + kv.y*wkc[4*k4+1] + kv.z*wkc[4*k4+2] + kv.w*wkc[4*k4+3];
        }
        __builtin_amdgcn_wave_barrier();
        float xs = has_ori ? xsrc[o*64 + lane] : xs0;
        atomicAdd(&x1row[o*64 + lane], xs * accm);
    }
}

// ---------------------------------------------------------------------------
// K5: MFMA node kernel (unchanged from round 4 — known good)
// ---------------------------------------------------------------------------
__global__ __launch_bounds__(256, 2) void node_mfma(
    const float* __restrict__ x1, const float* __restrict__ fk,
    const float* __restrict__ conv_b, const float* __restrict__ ln_g,
    const float* __restrict__ ln_b,
    const short* __restrict__ W1B, const float* __restrict__ b1,
    const short* __restrict__ W2B, const float* __restrict__ pb2,
    const float* __restrict__ Wr, const float* __restrict__ br,
    const float* __restrict__ x_old, float* __restrict__ x_new,
    float* __restrict__ racc, int has_res, int write_x)
{
    __shared__ short sA1[128*72];
    __shared__ short sA2[128*136];

    int tid = threadIdx.x;
    int blockRow = blockIdx.x * 128;

    {
        int rl = tid >> 1, hf = tid & 1;
        int row = blockRow + rl;
        int rc = row < N_ROWS ? row : N_ROWS - 1;
        int v = rc / 12, pp = rc % 12;
        float h[32];
        #pragma unroll
        for (int k = 0; k < 32; k++) h[k] = 0.f;
        const float* xv = x1 + (size_t)v*768 + hf*32;
        const float* fp = fk + (size_t)pp*768 + hf*32;
        for (int o = 0; o < 12; o++) {
            const float4* xa = (const float4*)(xv + o*64);
            const float4* fa = (const float4*)(fp + o*64);
            #pragma unroll
            for (int k4 = 0; k4 < 8; k4++) {
                float4 xd = xa[k4]; float4 fd = fa[k4];
                h[4*k4+0] += xd.x*fd.x; h[4*k4+1] += xd.y*fd.y;
                h[4*k4+2] += xd.z*fd.z; h[4*k4+3] += xd.w*fd.w;
            }
        }
        const float inv12 = 1.0f/12.0f;
        float sum = 0.f;
        #pragma unroll
        for (int k = 0; k < 32; k++) { h[k] = h[k]*inv12 + conv_b[hf*32 + k]; sum += h[k]; }
        sum += __shfl_xor(sum, 1);
        float mu = sum * (1.0f/64.0f);
        float var = 0.f;
        #pragma unroll
        for (int k = 0; k < 32; k++) { float xc = h[k] - mu; var += xc*xc; }
        var += __shfl_xor(var, 1);
        float rstd = rsqrtf(var*(1.0f/64.0f) + 1e-5f);
        short* dst = sA1 + rl*72 + hf*32;
        #pragma unroll
        for (int blk = 0; blk < 4; blk++) {
            union { short s[8]; int4 v4; } u;
            #pragma unroll
            for (int j = 0; j < 8; j++) {
                int k = blk*8 + j, c = hf*32 + k;
                u.s[j] = f2bf((h[k] - mu)*rstd*ln_g[c] + ln_b[c]);
            }
            *(int4*)(dst + blk*8) = u.v4;
        }
    }
    __syncthreads();

    int w   = tid >> 6;
    int l   = tid & 63;
    int m16 = l & 15, q = l >> 4;

    bfrag a1[2][2];
    #pragma unroll
    for (int i = 0; i < 2; i++) {
        int mt = 2*w + i;
        #pragma unroll
        for (int kc = 0; kc < 2; kc++)
            a1[i][kc] = *(const bfrag*)(sA1 + (mt*16 + m16)*72 + kc*32 + q*8);
    }

    f32x4 acc2[4][2];
    #pragma unroll
    for (int n = 0; n < 4; n++)
        #pragma unroll
        for (int i = 0; i < 2; i++)
            acc2[n][i] = (f32x4){0.f, 0.f, 0.f, 0.f};

    for (int ph = 0; ph < 2; ph++) {
        for (int ntl = 0; ntl < 8; ntl++) {
            int nt = ph*8 + ntl;
            f32x4 c0 = (f32x4){0.f,0.f,0.f,0.f};
            f32x4 c1 = (f32x4){0.f,0.f,0.f,0.f};
            #pragma unroll
            for (int kc = 0; kc < 2; kc++) {
                bfrag bb = *(const bfrag*)(W1B + (nt*16 + m16)*64 + kc*32 + q*8);
                c0 = __builtin_amdgcn_mfma_f32_16x16x32_bf16(a1[0][kc], bb, c0, 0, 0, 0);
                c1 = __builtin_amdgcn_mfma_f32_16x16x32_bf16(a1[1][kc], bb, c1, 0, 0, 0);
            }
            float bias = b1[nt*16 + m16];
            #pragma unroll
            for (int r = 0; r < 4; r++) {
                int r0 = (2*w)*16 + q*4 + r;
                int r1 = (2*w+1)*16 + q*4 + r;
                sA2[r0*136 + ntl*16 + m16] = f2bf(gelu_f(c0[r] + bias));
                sA2[r1*136 + ntl*16 + m16] = f2bf(gelu_f(c1[r] + bias));
            }
        }
        __syncthreads();
        for (int kc2 = 0; kc2 < 4; kc2++) {
            bfrag a2[2];
            #pragma unroll
            for (int i = 0; i < 2; i++)
                a2[i] = *(const bfrag*)(sA2 + ((2*w+i)*16 + m16)*136 + kc2*32 + q*8);
            #pragma unroll
            for (int nc = 0; nc < 4; nc++) {
                bfrag bb = *(const bfrag*)(W2B + (nc*16 + m16)*256 + ph*128 + kc2*32 + q*8);
                acc2[nc][0] = __builtin_amdgcn_mfma_f32_16x16x32_bf16(a2[0], bb, acc2[nc][0], 0, 0, 0);
                acc2[nc][1] = __builtin_amdgcn_mfma_f32_16x16x32_bf16(a2[1], bb, acc2[nc][1], 0, 0, 0);
            }
        }
        __syncthreads();
    }

    float p0[2][4], p1[2][4];
    #pragma unroll
    for (int i = 0; i < 2; i++) {
        #pragma unroll
        for (int r = 0; r < 4; r++) {
            int rowl = (2*w+i)*16 + q*4 + r;
            int row  = blockRow + rowl;
            bool ok  = row < N_ROWS;
            float vals[4];
            #pragma unroll
            for (int nc = 0; nc < 4; nc++) vals[nc] = acc2[nc][i][r] + pb2[nc*16 + m16];
            if (has_res && ok) {
                #pragma unroll
                for (int nc = 0; nc < 4; nc++) vals[nc] += x_old[(size_t)row*64 + nc*16 + m16];
            }
            if (write_x && ok) {
                #pragma unroll
                for (int nc = 0; nc < 4; nc++) x_new[(size_t)row*64 + nc*16 + m16] = vals[nc];
            }
            float q0 = 0.f, q1 = 0.f;
            #pragma unroll
            for (int nc = 0; nc < 4; nc++) {
                int c = nc*16 + m16;
                q0 += vals[nc]*Wr[2*c];
                q1 += vals[nc]*Wr[2*c + 1];
            }
            p0[i][r] = q0; p1[i][r] = q1;
        }
    }
    #pragma unroll
    for (int s = 1; s < 16; s <<= 1) {
        #pragma unroll
        for (int i = 0; i < 2; i++)
            #pragma unroll
            for (int r = 0; r < 4; r++) {
                p0[i][r] += __shfl_xor(p0[i][r], s);
                p1[i][r] += __shfl_xor(p1[i][r], s);
            }
    }
    if (m16 == 0) {
        #pragma unroll
        for (int i = 0; i < 2; i++)
            #pragma unroll
            for (int r = 0; r < 4; r++) {
                int row = blockRow + (2*w+i)*16 + q*4 + r;
                if (row < N_ROWS) {
                    atomicAdd(&racc[row*2 + 0], p0[i][r] + br[0]);
                    atomicAdd(&racc[row*2 + 1], p1[i][r] + br[1]);
                }
            }
    }
}

// ---------------------------------------------------------------------------
// K6: readout
// ---------------------------------------------------------------------------
__global__ __launch_bounds__(256) void final_kernel(
    const float* __restrict__ racc, const float* __restrict__ ori,
    const int* __restrict__ batch, float* __restrict__ out)
{
    int v = blockIdx.x*256 + threadIdx.x;
    if (v >= N_NODES) return;
    float srs = 0.f, vx = 0.f, vy = 0.f, vz = 0.f;
    #pragma unroll
    for (int p = 0; p < 12; p++) {
        float r0 = racc[v*24 + 2*p], r1 = racc[v*24 + 2*p + 1];
        srs += r0;
        vx += r1*ori[3*p]; vy += r1*ori[3*p+1]; vz += r1*ori[3*p+2];
    }
    const float sc = 1.0f/24.0f;
    int g = batch[v];
    atomicAdd(&out[g], srs*sc);
    atomicAdd(&out[16 + g*3 + 0], vx*sc);
    atomicAdd(&out[16 + g*3 + 1], vy*sc);
    atomicAdd(&out[16 + g*3 + 2], vz*sc);
}

extern "C" void kernel_launch(void* const* d_in, const int* in_sizes, int n_in,
                              void* d_out, int out_size, void* d_ws, size_t ws_size,
                              hipStream_t stream) {
    const float* pos    = (const float*)d_in[0];
    const float* f      = (const float*)d_in[1];
    const float* ori    = (const float*)d_in[2];
    const int*   ei     = (const int*)  d_in[3];
    const int*   batch  = (const int*)  d_in[4];
    const float* Wb1    = (const float*)d_in[5];
    const float* bb1    = (const float*)d_in[6];
    const float* Wb2    = (const float*)d_in[7];
    const float* bb2    = (const float*)d_in[8];
    const float* Wo1    = (const float*)d_in[9];
    const float* bo1    = (const float*)d_in[10];
    const float* Wo2    = (const float*)d_in[11];
    const float* bo2    = (const float*)d_in[12];
    const float* We     = (const float*)d_in[13];
    const float* Wk     = (const float*)d_in[14];
    const float* Wf     = (const float*)d_in[15];
    const float* conv_b = (const float*)d_in[16];
    const float* ln_g   = (const float*)d_in[17];
    const float* ln_b   = (const float*)d_in[18];
    const float* W1     = (const float*)d_in[19];
    const float* b1     = (const float*)d_in[20];
    const float* W2     = (const float*)d_in[21];
    const float* b2     = (const float*)d_in[22];
    const float* Wr     = (const float*)d_in[23];
    const float* br     = (const float*)d_in[24];
    float* out = (float*)d_out;

    float* ws   = (float*)d_ws;
    float* xe   = ws;                       //   640,000 f32
    float* xs1  = xe   + 640000;            // 7,680,000
    float* x1a  = xs1  + 7680000;           // 7,680,000
    float* racc = x1a  + 7680000;           //   240,000
    float* fkb  = racc + 240000;            //    18,432
    short* w1b  = (short*)(fkb + 18432);    //    32,768 shorts (2 layers)
    short* w2b  = w1b + 32768;              //    32,768 shorts
    short* w1k  = w2b + 32768;              //     2,048 shorts
    short* w2k  = w1k + 2048;               //     4,096 shorts
    short* pad_ = w2k + 4096;               // align to 4B
    __hip_bfloat16* kbb = (__hip_bfloat16*)(pad_ + 2048);   // 61,440,000 bf16

    hipMemsetAsync(out,  0, 64*sizeof(float), stream);
    hipMemsetAsync(racc, 0, 240000*sizeof(float), stream);
    hipMemsetAsync(x1a,  0, 7680000*sizeof(float), stream);

    prep_weights<<<3,    256, 0, stream>>>(W1, W2, Wb1, Wb2, w1b, w2b, w1k, w2k);
    ori_kernel  <<<144,  64, 0, stream>>>(ori, Wo1, bo1, Wo2, bo2, Wf, fkb);
    embed_kernel<<<2500, 256, 0, stream>>>(f, We, xe);
    kb_mfma     <<<3750, 256, 0, stream>>>(pos, ori, w1k, bb1, w2k, bb2, ei, kbb);

    // layer 0
    scatter_kernel<<<20000,256, 0, stream>>>(kbb, Wk, ei, xe, x1a, /*has_ori=*/0);
    node_mfma     <<<938,  256, 0, stream>>>(x1a, fkb, conv_b, ln_g, ln_b,
                                             w1b, b1, w2b, b2, Wr, br,
                                             xs1, xs1, racc, /*res=*/0, /*write=*/1);
    // layer 1
    hipMemsetAsync(x1a, 0, 7680000*sizeof(float), stream);
    scatter_kernel<<<20000,256, 0, stream>>>(kbb, Wk + 4096, ei, xs1, x1a, /*has_ori=*/1);
    node_mfma     <<<938,  256, 0, stream>>>(x1a, fkb + 9216, conv_b + 64, ln_g + 64, ln_b + 64,
                                             w1b + 16384, b1 + 256, w2b + 16384, b2 + 64,
                                             Wr + 128, br + 2,
                                             xs1, xs1, racc, /*res=*/1, /*write=*/0);

    final_kernel<<<40,   256, 0, stream>>>(racc, ori, batch, out);
}

// Round 6
// 1215.917 us; speedup vs baseline: 1.7542x; 1.0954x over previous
//
#include <hip/hip_runtime.h>
#include <hip/hip_bf16.h>
#include <math.h>

#define N_NODES 10000
#define N_EDGES 80000
#define N_ORI   12
#define N_ROWS  (N_NODES * N_ORI)
#define N_EROWS (N_EDGES * N_ORI)

typedef __attribute__((ext_vector_type(8))) short bfrag;   // 8 bf16 = 4 VGPRs
typedef __attribute__((ext_vector_type(4))) float f32x4;

__device__ __forceinline__ float gelu_f(float x) {
    return 0.5f * x * (1.0f + erff(x * 0.70710678118654752440f));
}
__device__ __forceinline__ short f2bf(float x) {
    __hip_bfloat16 h = __float2bfloat16(x);
    return *reinterpret_cast<short*>(&h);
}

// ---------------------------------------------------------------------------
// K0: weight prep.
// blocks 0,1 (l): W1B[l][t][k] (256x64); W2B[l][c][t] (64x256)
// block 2:        W1K[t][k0..31] (64x32, k>=30 zero); W2K[c][t] (64x64)
// block 3:        WkB[l][c][k] (2x64x64) from Wk[l][k][c]
// ---------------------------------------------------------------------------
__global__ __launch_bounds__(256) void prep_weights(
    const float* __restrict__ W1, const float* __restrict__ W2,
    const float* __restrict__ Wb1, const float* __restrict__ Wb2,
    const float* __restrict__ Wk,
    short* __restrict__ W1B, short* __restrict__ W2B,
    short* __restrict__ W1K, short* __restrict__ W2K,
    short* __restrict__ WkB)
{
    if (blockIdx.x < 2) {
        int l = blockIdx.x;
        const float* w1 = W1 + l*16384; short* w1b = W1B + l*16384;
        const float* w2 = W2 + l*16384; short* w2b = W2B + l*16384;
        for (int i = threadIdx.x; i < 16384; i += 256) {
            int k = i >> 8, t = i & 255;          // W1[k][t]
            w1b[t*64 + k] = f2bf(w1[i]);
            int t2 = i >> 6, c = i & 63;          // W2[t][c]
            w2b[c*256 + t2] = f2bf(w2[i]);
        }
    } else if (blockIdx.x == 2) {
        for (int i = threadIdx.x; i < 2048; i += 256) {
            int t = i >> 5, k = i & 31;
            W1K[i] = (k < 30) ? f2bf(Wb1[k*64 + t]) : (short)0;
        }
        for (int i = threadIdx.x; i < 4096; i += 256) {
            int c = i >> 6, t = i & 63;
            W2K[i] = f2bf(Wb2[t*64 + c]);
        }
    } else {
        for (int i = threadIdx.x; i < 8192; i += 256) {
            int l = i >> 12, rem = i & 4095, k = rem >> 6, c = rem & 63;
            WkB[l*4096 + c*64 + k] = f2bf(Wk[l*4096 + k*64 + c]);
        }
    }
}

// ---------------------------------------------------------------------------
// K1: kb_ori MLP + fk[l][p][o][c] = (kb_ori @ Wf[l]).
// ---------------------------------------------------------------------------
__global__ __launch_bounds__(64) void ori_kernel(
    const float* __restrict__ ori, const float* __restrict__ Wo1,
    const float* __restrict__ bo1, const float* __restrict__ Wo2,
    const float* __restrict__ bo2, const float* __restrict__ Wf,
    float* __restrict__ fkb)
{
    __shared__ float sh[64];
    __shared__ float skb[64];
    int i = blockIdx.x / 12, j = blockIdx.x % 12;
    int lane = threadIdx.x;
    float s = ori[3*i]*ori[3*j] + ori[3*i+1]*ori[3*j+1] + ori[3*i+2]*ori[3*j+2];
    float p1 = s, p2 = s*s, p3 = p2*s, p4 = p3*s;
    float acc = bo1[lane] + p1*Wo1[lane] + p2*Wo1[64+lane] + p3*Wo1[128+lane] + p4*Wo1[192+lane];
    sh[lane] = gelu_f(acc);
    __syncthreads();
    float acc2 = bo2[lane];
    #pragma unroll
    for (int k = 0; k < 64; k++) acc2 += sh[k] * Wo2[k*64 + lane];
    skb[lane] = gelu_f(acc2);
    __syncthreads();
    for (int l = 0; l < 2; l++) {
        float a = 0.f;
        #pragma unroll
        for (int k = 0; k < 64; k++) a += skb[k] * Wf[l*4096 + k*64 + lane];
        fkb[l*9216 + i*768 + j*64 + lane] = a;
    }
}

// ---------------------------------------------------------------------------
// K2: x = f @ We
// ---------------------------------------------------------------------------
__global__ __launch_bounds__(256) void embed_kernel(
    const float* __restrict__ f, const float* __restrict__ We, float* __restrict__ xe)
{
    int v = blockIdx.x*4 + (threadIdx.x >> 6);
    int lane = threadIdx.x & 63;
    if (v >= N_NODES) return;
    float acc = 0.f;
    #pragma unroll
    for (int k = 0; k < 16; k++) acc += f[v*16 + k] * We[k*64 + lane];
    xe[v*64 + lane] = acc;
}

// ---------------------------------------------------------------------------
// K3 (v2): kb MLP via MFMA + akb = kb@Wk for BOTH layers.
// Layer 0: akb0 stays in regs -> fused scatter: atomicAdd(x1, akb0*xe[src]).
// Layer 1: akb1 stored bf16 for the lean scatter.
// Each wave owns rows [w*64, w*64+64) of sH -> no barriers after FFN1 sync.
// ---------------------------------------------------------------------------
__global__ __launch_bounds__(256, 2) void kb_mfma(
    const float* __restrict__ pos, const float* __restrict__ ori,
    const short* __restrict__ W1K, const float* __restrict__ bb1,
    const short* __restrict__ W2K, const float* __restrict__ bb2,
    const short* __restrict__ WkB, const int* __restrict__ ei,
    const float* __restrict__ xe, float* __restrict__ x1a,
    __hip_bfloat16* __restrict__ akb1)
{
    __shared__ short sF[256*40];
    __shared__ short sH[256*72];
    __shared__ float sEnv[256];

    int tid = threadIdx.x;
    int blockRow = blockIdx.x * 256;

    // ---- Phase A: features ----
    {
        int row = blockRow + tid;
        int e = row / 12, o = row - e*12;
        int sn = ei[e], dn = ei[N_EDGES + e];
        float rx = pos[sn*3+0] - pos[dn*3+0];
        float ry = pos[sn*3+1] - pos[dn*3+1];
        float rz = pos[sn*3+2] - pos[dn*3+2];
        float d  = sqrtf(rx*rx + ry*ry + rz*rz);
        float u2 = d*d, u4 = u2*u2, u6 = u4*u2;
        float env = (d < 1.0f) ? (1.0f - 28.0f*u6 + 48.0f*u6*d - 21.0f*u6*u2) : 0.0f;
        sEnv[tid] = env;

        float ox = ori[3*o], oy = ori[3*o+1], oz = ori[3*o+2];
        float a  = rx*ox + ry*oy + rz*oz;
        float qx = rx - a*ox, qy = ry - a*oy, qz = rz - a*oz;
        float b  = sqrtf(qx*qx + qy*qy + qz*qz);

        float fv[32];
        fv[0] = a; fv[1] = b;
        fv[2] = a*a; fv[3] = a*b; fv[4] = b*a; fv[5] = b*b;
        #pragma unroll
        for (int i = 0; i < 4; i++) { fv[6+2*i] = fv[2+i]*a; fv[7+2*i] = fv[2+i]*b; }
        #pragma unroll
        for (int i = 0; i < 8; i++) { fv[14+2*i] = fv[6+i]*a; fv[15+2*i] = fv[6+i]*b; }
        fv[30] = 0.f; fv[31] = 0.f;

        short* dst = sF + tid*40;
        #pragma unroll
        for (int blk = 0; blk < 4; blk++) {
            union { short s[8]; int4 v4; } u;
            #pragma unroll
            for (int j = 0; j < 8; j++) u.s[j] = f2bf(fv[blk*8 + j]);
            *(int4*)(dst + blk*8) = u.v4;
        }
    }
    __syncthreads();

    int w = tid >> 6, l = tid & 63;
    int m16 = l & 15, q = l >> 4;

    // ---- FFN1: K=32 ----
    bfrag a1[4];
    #pragma unroll
    for (int mt = 0; mt < 4; mt++)
        a1[mt] = *(const bfrag*)(sF + ((w*4 + mt)*16 + m16)*40 + q*8);

    #pragma unroll
    for (int nt = 0; nt < 4; nt++) {
        bfrag bb = *(const bfrag*)(W1K + (nt*16 + m16)*32 + q*8);
        float bias = bb1[nt*16 + m16];
        #pragma unroll
        for (int mt = 0; mt < 4; mt++) {
            f32x4 acc = (f32x4){0.f,0.f,0.f,0.f};
            acc = __builtin_amdgcn_mfma_f32_16x16x32_bf16(a1[mt], bb, acc, 0, 0, 0);
            #pragma unroll
            for (int r = 0; r < 4; r++) {
                int rl = (w*4 + mt)*16 + q*4 + r;
                sH[rl*72 + nt*16 + m16] = f2bf(gelu_f(acc[r] + bias));
            }
        }
    }
    __syncthreads();

    // ---- FFN2: K=64 -> kb = gelu(.)*env, written back into sH (own rows) ----
    bfrag a2[4][2];
    #pragma unroll
    for (int mt = 0; mt < 4; mt++)
        #pragma unroll
        for (int kc = 0; kc < 2; kc++)
            a2[mt][kc] = *(const bfrag*)(sH + ((w*4 + mt)*16 + m16)*72 + kc*32 + q*8);

    #pragma unroll
    for (int nt = 0; nt < 4; nt++) {
        f32x4 acc[4];
        #pragma unroll
        for (int mt = 0; mt < 4; mt++) acc[mt] = (f32x4){0.f,0.f,0.f,0.f};
        #pragma unroll
        for (int kc = 0; kc < 2; kc++) {
            bfrag bb = *(const bfrag*)(W2K + (nt*16 + m16)*64 + kc*32 + q*8);
            #pragma unroll
            for (int mt = 0; mt < 4; mt++)
                acc[mt] = __builtin_amdgcn_mfma_f32_16x16x32_bf16(a2[mt][kc], bb, acc[mt], 0, 0, 0);
        }
        float bias = bb2[nt*16 + m16];
        #pragma unroll
        for (int mt = 0; mt < 4; mt++) {
            #pragma unroll
            for (int r = 0; r < 4; r++) {
                int rl = (w*4 + mt)*16 + q*4 + r;
                sH[rl*72 + nt*16 + m16] = f2bf(gelu_f(acc[mt][r] + bias) * sEnv[rl]);
            }
        }
    }
    // wave-local: each wave reads/writes only its own 64 rows of sH; DS ops
    // within a wave are ordered -> no barrier needed.

    // ---- akb GEMMs: kb @ Wk[l] ----
    bfrag a3[4][2];
    #pragma unroll
    for (int mt = 0; mt < 4; mt++)
        #pragma unroll
        for (int kc = 0; kc < 2; kc++)
            a3[mt][kc] = *(const bfrag*)(sH + ((w*4 + mt)*16 + m16)*72 + kc*32 + q*8);

    // per-lane row info (16 rows)
    int eArr[4][4], oArr[4][4], snArr[4][4], dnArr[4][4];
    #pragma unroll
    for (int mt = 0; mt < 4; mt++)
        #pragma unroll
        for (int r = 0; r < 4; r++) {
            int R = blockRow + (w*4 + mt)*16 + q*4 + r;
            int e = R / 12;
            eArr[mt][r] = e; oArr[mt][r] = R - e*12;
            snArr[mt][r] = ei[e]; dnArr[mt][r] = ei[N_EDGES + e];
        }

    // layer 0: compute akb0 and scatter immediately
    #pragma unroll
    for (int nt = 0; nt < 4; nt++) {
        f32x4 acc[4];
        #pragma unroll
        for (int mt = 0; mt < 4; mt++) acc[mt] = (f32x4){0.f,0.f,0.f,0.f};
        #pragma unroll
        for (int kc = 0; kc < 2; kc++) {
            bfrag bb = *(const bfrag*)(WkB + (nt*16 + m16)*64 + kc*32 + q*8);
            #pragma unroll
            for (int mt = 0; mt < 4; mt++)
                acc[mt] = __builtin_amdgcn_mfma_f32_16x16x32_bf16(a3[mt][kc], bb, acc[mt], 0, 0, 0);
        }
        int col = nt*16 + m16;
        #pragma unroll
        for (int mt = 0; mt < 4; mt++)
            #pragma unroll
            for (int r = 0; r < 4; r++) {
                float val = acc[mt][r] * xe[snArr[mt][r]*64 + col];
                atomicAdd(&x1a[(size_t)dnArr[mt][r]*768 + oArr[mt][r]*64 + col], val);
            }
    }
    // layer 1: compute akb1 and store bf16
    #pragma unroll
    for (int nt = 0; nt < 4; nt++) {
        f32x4 acc[4];
        #pragma unroll
        for (int mt = 0; mt < 4; mt++) acc[mt] = (f32x4){0.f,0.f,0.f,0.f};
        #pragma unroll
        for (int kc = 0; kc < 2; kc++) {
            bfrag bb = *(const bfrag*)(WkB + 4096 + (nt*16 + m16)*64 + kc*32 + q*8);
            #pragma unroll
            for (int mt = 0; mt < 4; mt++)
                acc[mt] = __builtin_amdgcn_mfma_f32_16x16x32_bf16(a3[mt][kc], bb, acc[mt], 0, 0, 0);
        }
        int col = nt*16 + m16;
        #pragma unroll
        for (int mt = 0; mt < 4; mt++)
            #pragma unroll
            for (int r = 0; r < 4; r++) {
                int R = blockRow + (w*4 + mt)*16 + q*4 + r;
                akb1[(size_t)R*64 + col] = __float2bfloat16(acc[mt][r]);
            }
    }
}

// ---------------------------------------------------------------------------
// K4 (lean): layer-1 scatter: x1[dst,o,c] += x_in[src,o,c] * akb1[e,o,c]
// ---------------------------------------------------------------------------
__global__ __launch_bounds__(256) void scatter_lean(
    const __hip_bfloat16* __restrict__ akb, const int* __restrict__ ei,
    const float* __restrict__ x_in, float* __restrict__ x1)
{
    int w = threadIdx.x >> 6, lane = threadIdx.x & 63;
    int e  = blockIdx.x*4 + w;
    int sn = ei[e], dn = ei[N_EDGES + e];
    const __hip_bfloat16* ak = akb + (size_t)e*768;
    const float* xsrc = x_in + (size_t)sn*768;
    float* xd = x1 + (size_t)dn*768;
    #pragma unroll
    for (int o = 0; o < N_ORI; o++) {
        float a  = __bfloat162float(ak[o*64 + lane]);
        float xs = xsrc[o*64 + lane];
        atomicAdd(&xd[o*64 + lane], a*xs);
    }
}

// ---------------------------------------------------------------------------
// K5: MFMA node kernel (unchanged — known good)
// ---------------------------------------------------------------------------
__global__ __launch_bounds__(256, 2) void node_mfma(
    const float* __restrict__ x1, const float* __restrict__ fk,
    const float* __restrict__ conv_b, const float* __restrict__ ln_g,
    const float* __restrict__ ln_b,
    const short* __restrict__ W1B, const float* __restrict__ b1,
    const short* __restrict__ W2B, const float* __restrict__ pb2,
    const float* __restrict__ Wr, const float* __restrict__ br,
    const float* __restrict__ x_old, float* __restrict__ x_new,
    float* __restrict__ racc, int has_res, int write_x)
{
    __shared__ short sA1[128*72];
    __shared__ short sA2[128*136];

    int tid = threadIdx.x;
    int blockRow = blockIdx.x * 128;

    {
        int rl = tid >> 1, hf = tid & 1;
        int row = blockRow + rl;
        int rc = row < N_ROWS ? row : N_ROWS - 1;
        int v = rc / 12, pp = rc % 12;
        float h[32];
        #pragma unroll
        for (int k = 0; k < 32; k++) h[k] = 0.f;
        const float* xv = x1 + (size_t)v*768 + hf*32;
        const float* fp = fk + (size_t)pp*768 + hf*32;
        for (int o = 0; o < 12; o++) {
            const float4* xa = (const float4*)(xv + o*64);
            const float4* fa = (const float4*)(fp + o*64);
            #pragma unroll
            for (int k4 = 0; k4 < 8; k4++) {
                float4 xd = xa[k4]; float4 fd = fa[k4];
                h[4*k4+0] += xd.x*fd.x; h[4*k4+1] += xd.y*fd.y;
                h[4*k4+2] += xd.z*fd.z; h[4*k4+3] += xd.w*fd.w;
            }
        }
        const float inv12 = 1.0f/12.0f;
        float sum = 0.f;
        #pragma unroll
        for (int k = 0; k < 32; k++) { h[k] = h[k]*inv12 + conv_b[hf*32 + k]; sum += h[k]; }
        sum += __shfl_xor(sum, 1);
        float mu = sum * (1.0f/64.0f);
        float var = 0.f;
        #pragma unroll
        for (int k = 0; k < 32; k++) { float xc = h[k] - mu; var += xc*xc; }
        var += __shfl_xor(var, 1);
        float rstd = rsqrtf(var*(1.0f/64.0f) + 1e-5f);
        short* dst = sA1 + rl*72 + hf*32;
        #pragma unroll
        for (int blk = 0; blk < 4; blk++) {
            union { short s[8]; int4 v4; } u;
            #pragma unroll
            for (int j = 0; j < 8; j++) {
                int k = blk*8 + j, c = hf*32 + k;
                u.s[j] = f2bf((h[k] - mu)*rstd*ln_g[c] + ln_b[c]);
            }
            *(int4*)(dst + blk*8) = u.v4;
        }
    }
    __syncthreads();

    int w   = tid >> 6;
    int l   = tid & 63;
    int m16 = l & 15, q = l >> 4;

    bfrag a1[2][2];
    #pragma unroll
    for (int i = 0; i < 2; i++) {
        int mt = 2*w + i;
        #pragma unroll
        for (int kc = 0; kc < 2; kc++)
            a1[i][kc] = *(const bfrag*)(sA1 + (mt*16 + m16)*72 + kc*32 + q*8);
    }

    f32x4 acc2[4][2];
    #pragma unroll
    for (int n = 0; n < 4; n++)
        #pragma unroll
        for (int i = 0; i < 2; i++)
            acc2[n][i] = (f32x4){0.f, 0.f, 0.f, 0.f};

    for (int ph = 0; ph < 2; ph++) {
        for (int ntl = 0; ntl < 8; ntl++) {
            int nt = ph*8 + ntl;
            f32x4 c0 = (f32x4){0.f,0.f,0.f,0.f};
            f32x4 c1 = (f32x4){0.f,0.f,0.f,0.f};
            #pragma unroll
            for (int kc = 0; kc < 2; kc++) {
                bfrag bb = *(const bfrag*)(W1B + (nt*16 + m16)*64 + kc*32 + q*8);
                c0 = __builtin_amdgcn_mfma_f32_16x16x32_bf16(a1[0][kc], bb, c0, 0, 0, 0);
                c1 = __builtin_amdgcn_mfma_f32_16x16x32_bf16(a1[1][kc], bb, c1, 0, 0, 0);
            }
            float bias = b1[nt*16 + m16];
            #pragma unroll
            for (int r = 0; r < 4; r++) {
                int r0 = (2*w)*16 + q*4 + r;
                int r1 = (2*w+1)*16 + q*4 + r;
                sA2[r0*136 + ntl*16 + m16] = f2bf(gelu_f(c0[r] + bias));
                sA2[r1*136 + ntl*16 + m16] = f2bf(gelu_f(c1[r] + bias));
            }
        }
        __syncthreads();
        for (int kc2 = 0; kc2 < 4; kc2++) {
            bfrag a2[2];
            #pragma unroll
            for (int i = 0; i < 2; i++)
                a2[i] = *(const bfrag*)(sA2 + ((2*w+i)*16 + m16)*136 + kc2*32 + q*8);
            #pragma unroll
            for (int nc = 0; nc < 4; nc++) {
                bfrag bb = *(const bfrag*)(W2B + (nc*16 + m16)*256 + ph*128 + kc2*32 + q*8);
                acc2[nc][0] = __builtin_amdgcn_mfma_f32_16x16x32_bf16(a2[0], bb, acc2[nc][0], 0, 0, 0);
                acc2[nc][1] = __builtin_amdgcn_mfma_f32_16x16x32_bf16(a2[1], bb, acc2[nc][1], 0, 0, 0);
            }
        }
        __syncthreads();
    }

    float p0[2][4], p1[2][4];
    #pragma unroll
    for (int i = 0; i < 2; i++) {
        #pragma unroll
        for (int r = 0; r < 4; r++) {
            int rowl = (2*w+i)*16 + q*4 + r;
            int row  = blockRow + rowl;
            bool ok  = row < N_ROWS;
            float vals[4];
            #pragma unroll
            for (int nc = 0; nc < 4; nc++) vals[nc] = acc2[nc][i][r] + pb2[nc*16 + m16];
            if (has_res && ok) {
                #pragma unroll
                for (int nc = 0; nc < 4; nc++) vals[nc] += x_old[(size_t)row*64 + nc*16 + m16];
            }
            if (write_x && ok) {
                #pragma unroll
                for (int nc = 0; nc < 4; nc++) x_new[(size_t)row*64 + nc*16 + m16] = vals[nc];
            }
            float q0 = 0.f, q1 = 0.f;
            #pragma unroll
            for (int nc = 0; nc < 4; nc++) {
                int c = nc*16 + m16;
                q0 += vals[nc]*Wr[2*c];
                q1 += vals[nc]*Wr[2*c + 1];
            }
            p0[i][r] = q0; p1[i][r] = q1;
        }
    }
    #pragma unroll
    for (int s = 1; s < 16; s <<= 1) {
        #pragma unroll
        for (int i = 0; i < 2; i++)
            #pragma unroll
            for (int r = 0; r < 4; r++) {
                p0[i][r] += __shfl_xor(p0[i][r], s);
                p1[i][r] += __shfl_xor(p1[i][r], s);
            }
    }
    if (m16 == 0) {
        #pragma unroll
        for (int i = 0; i < 2; i++)
            #pragma unroll
            for (int r = 0; r < 4; r++) {
                int row = blockRow + (2*w+i)*16 + q*4 + r;
                if (row < N_ROWS) {
                    atomicAdd(&racc[row*2 + 0], p0[i][r] + br[0]);
                    atomicAdd(&racc[row*2 + 1], p1[i][r] + br[1]);
                }
            }
    }
}

// ---------------------------------------------------------------------------
// K6: readout
// ---------------------------------------------------------------------------
__global__ __launch_bounds__(256) void final_kernel(
    const float* __restrict__ racc, const float* __restrict__ ori,
    const int* __restrict__ batch, float* __restrict__ out)
{
    int v = blockIdx.x*256 + threadIdx.x;
    if (v >= N_NODES) return;
    float srs = 0.f, vx = 0.f, vy = 0.f, vz = 0.f;
    #pragma unroll
    for (int p = 0; p < 12; p++) {
        float r0 = racc[v*24 + 2*p], r1 = racc[v*24 + 2*p + 1];
        srs += r0;
        vx += r1*ori[3*p]; vy += r1*ori[3*p+1]; vz += r1*ori[3*p+2];
    }
    const float sc = 1.0f/24.0f;
    int g = batch[v];
    atomicAdd(&out[g], srs*sc);
    atomicAdd(&out[16 + g*3 + 0], vx*sc);
    atomicAdd(&out[16 + g*3 + 1], vy*sc);
    atomicAdd(&out[16 + g*3 + 2], vz*sc);
}

extern "C" void kernel_launch(void* const* d_in, const int* in_sizes, int n_in,
                              void* d_out, int out_size, void* d_ws, size_t ws_size,
                              hipStream_t stream) {
    const float* pos    = (const float*)d_in[0];
    const float* f      = (const float*)d_in[1];
    const float* ori    = (const float*)d_in[2];
    const int*   ei     = (const int*)  d_in[3];
    const int*   batch  = (const int*)  d_in[4];
    const float* Wb1    = (const float*)d_in[5];
    const float* bb1    = (const float*)d_in[6];
    const float* Wb2    = (const float*)d_in[7];
    const float* bb2    = (const float*)d_in[8];
    const float* Wo1    = (const float*)d_in[9];
    const float* bo1    = (const float*)d_in[10];
    const float* Wo2    = (const float*)d_in[11];
    const float* bo2    = (const float*)d_in[12];
    const float* We     = (const float*)d_in[13];
    const float* Wk     = (const float*)d_in[14];
    const float* Wf     = (const float*)d_in[15];
    const float* conv_b = (const float*)d_in[16];
    const float* ln_g   = (const float*)d_in[17];
    const float* ln_b   = (const float*)d_in[18];
    const float* W1     = (const float*)d_in[19];
    const float* b1     = (const float*)d_in[20];
    const float* W2     = (const float*)d_in[21];
    const float* b2     = (const float*)d_in[22];
    const float* Wr     = (const float*)d_in[23];
    const float* br     = (const float*)d_in[24];
    float* out = (float*)d_out;

    float* ws   = (float*)d_ws;
    float* xe   = ws;                       //   640,000 f32
    float* xs1  = xe   + 640000;            // 7,680,000
    float* x1a  = xs1  + 7680000;           // 7,680,000
    float* racc = x1a  + 7680000;           //   240,000
    float* fkb  = racc + 240000;            //    18,432
    short* w1b  = (short*)(fkb + 18432);    //    32,768 shorts (2 layers)
    short* w2b  = w1b + 32768;              //    32,768 shorts
    short* w1k  = w2b + 32768;              //     2,048 shorts
    short* w2k  = w1k + 2048;               //     4,096 shorts
    short* wkb  = w2k + 4096;               //     8,192 shorts
    short* pad_ = wkb + 8192;               // align
    __hip_bfloat16* akb1 = (__hip_bfloat16*)(pad_ + 2048);  // 61,440,000 bf16

    hipMemsetAsync(out,  0, 64*sizeof(float), stream);
    hipMemsetAsync(racc, 0, 240000*sizeof(float), stream);
    hipMemsetAsync(x1a,  0, 7680000*sizeof(float), stream);

    prep_weights<<<4,    256, 0, stream>>>(W1, W2, Wb1, Wb2, Wk,
                                           w1b, w2b, w1k, w2k, wkb);
    ori_kernel  <<<144,  64, 0, stream>>>(ori, Wo1, bo1, Wo2, bo2, Wf, fkb);
    embed_kernel<<<2500, 256, 0, stream>>>(f, We, xe);

    // kb MLP + akb GEMMs + fused layer-0 scatter + akb1 store
    kb_mfma     <<<3750, 256, 0, stream>>>(pos, ori, w1k, bb1, w2k, bb2,
                                           wkb, ei, xe, x1a, akb1);

    // layer 0 node
    node_mfma   <<<938,  256, 0, stream>>>(x1a, fkb, conv_b, ln_g, ln_b,
                                           w1b, b1, w2b, b2, Wr, br,
                                           xs1, xs1, racc, /*res=*/0, /*write=*/1);
    // layer 1
    hipMemsetAsync(x1a, 0, 7680000*sizeof(float), stream);
    scatter_lean<<<20000,256, 0, stream>>>(akb1, ei, xs1, x1a);
    node_mfma   <<<938,  256, 0, stream>>>(x1a, fkb + 9216, conv_b + 64, ln_g + 64, ln_b + 64,
                                           w1b + 16384, b1 + 256, w2b + 16384, b2 + 64,
                                           Wr + 128, br + 2,
                                           xs1, xs1, racc, /*res=*/1, /*write=*/0);

    final_kernel<<<40,   256, 0, stream>>>(racc, ori, batch, out);
}